// Round 8
// baseline (356.722 us; speedup 1.0000x reference)
//
#include <hip/hip_runtime.h>
#include <hip/hip_cooperative_groups.h>
#include <cstdint>
#include <cstddef>

namespace cg = cooperative_groups;

#define NB 8
#define NTOK 2048
#define TOKENS (NB * NTOK)   // 16384
#define D 1024
#define E 64
#define CAP 40
#define EC (E * CAP)         // 2560
#define OUT_TENSOR ((size_t)TOKENS * EC)  // 41943040
#define CHUNKS 32
#define CHTOK 64
#define KC 64                // gemm k-chunk (floats)

#define TOTAL_F4 20971520ull // (2*OUT_TENSOR)/4
#define PH0F4 131072ull      // phase-0 fixed fill (256 gemm blocks x 512 f4)
#define CHUNK_F4 4096        // 64 KB fill chunks
#define NCHUNK 5088          // (TOTAL_F4 - PH0F4) / CHUNK_F4, exact

typedef __attribute__((ext_vector_type(8))) short short8v;
typedef __attribute__((ext_vector_type(4))) float f32x4;

__device__ __forceinline__ unsigned short f2bf(float f) {
  unsigned u = __float_as_uint(f);
  unsigned r = (u + 0x7FFFu + ((u >> 16) & 1u)) >> 16;   // RNE
  return (unsigned short)r;
}

__device__ __forceinline__ void gload_lds16(const void* g, void* l) {
  __builtin_amdgcn_global_load_lds(
      (const __attribute__((address_space(1))) void*)g,
      (__attribute__((address_space(3))) void*)l, 16, 0, 0);
}

// Single cooperative kernel. 512 blocks x 256 threads, 48 KB LDS -> 2/CU safe.
// Role striping in groups of 8 (uniform over XCDs): (bid>>3)&1==0 -> gemm role.
__global__ __launch_bounds__(256, 2) void k_mega(
    const float* __restrict__ x, const float* __restrict__ w,
    const float* __restrict__ noise,
    int* __restrict__ i1o, int* __restrict__ i2o,
    float* __restrict__ g1o, float* __restrict__ g2o,
    float* __restrict__ proxyacc, int* __restrict__ count1,
    float* __restrict__ zpart, unsigned short* __restrict__ wT,
    int4* __restrict__ tokinfo, int* __restrict__ ctr, int* __restrict__ done,
    float* __restrict__ out) {
  __shared__ union {
    struct { float As[2][64 * KC]; unsigned short Bs[2][64 * KC]; } g;  // 48 KB
    struct { unsigned char pos1c[NTOK]; unsigned char pos2c[NTOK];
             int cnt1[CHUNKS][E]; int cnt2[CHUNKS][E]; } p;             // 20 KB
    float red[256];
    int chunk;
  } u;

  const int bid = blockIdx.x;
  const int tid = threadIdx.x;
  const bool is_gemm = ((bid >> 3) & 1) == 0;
  const int role_i = (bid >> 4) * 8 + (bid & 7);   // 0..255 within role
  float4* const o4 = reinterpret_cast<float4*>(out);
  const float4 z4 = make_float4(0.f, 0.f, 0.f, 0.f);

  // ---------------- Phase 0: wT transpose (fill role) + fixed fill (gemm role) ----------------
  if (bid == 0 && tid == 0) { *ctr = 0; *done = 0; }
  if (is_gemm) {
    const size_t base = (size_t)role_i * 512;
#pragma unroll
    for (int i = 0; i < 2; ++i) o4[base + 256 * i + tid] = z4;
  } else {
    int gid = role_i * 256 + tid;                  // 65536 total
    int e = gid >> 10, k = gid & 1023;
    wT[gid] = f2bf(w[k * E + e]);
    if (bid == 8 && tid < 128)
      reinterpret_cast<float4*>(proxyacc)[tid] = z4;   // 512 floats
  }
  cg::this_grid().sync();

  // ---------------- Phase 1: gemm+gate (gemm role) || work-stealing fill ----------------
  if (is_gemm) {
    const int gi = role_i;
    const int m0 = gi * 64;
    const int l = tid & 63;
    const int wv = tid >> 6;
    const int h = l >> 4;
    const int r = l & 15;
    const int x7 = l & 7;

    f32x4 acc[4];
#pragma unroll
    for (int f = 0; f < 4; ++f) acc[f] = (f32x4){0.f, 0.f, 0.f, 0.f};

#define STAGE(BUF, KCOFF)                                                            \
  {                                                                                  \
    _Pragma("unroll") for (int i = 0; i < 4; ++i) {                                  \
      int flat = tid + 256 * i;                                                      \
      int row = flat >> 4, slot = flat & 15;                                         \
      const float* g = x + (size_t)(m0 + row) * D + (KCOFF) + 4 * (slot ^ (row & 7)); \
      gload_lds16(g, (char*)&u.g.As[BUF][0] + (flat >> 6) * 1024);                   \
    }                                                                                \
    _Pragma("unroll") for (int i = 0; i < 2; ++i) {                                  \
      int flat = tid + 256 * i;                                                      \
      int e = flat >> 3, slot = flat & 7;                                            \
      const unsigned short* g = wT + (size_t)e * D + (KCOFF) + 8 * (slot ^ (e & 7)); \
      gload_lds16(g, (char*)&u.g.Bs[BUF][0] + (flat >> 6) * 1024);                   \
    }                                                                                \
  }

    STAGE(0, 0);
    __syncthreads();
    int buf = 0;
    for (int c = 0; c < 16; ++c) {
      if (c < 15) STAGE(buf ^ 1, (c + 1) * KC);
      const float* arow = &u.g.As[buf][(16 * wv + r) * KC];
#pragma unroll
      for (int s = 0; s < 2; ++s) {
        int a0 = (8 * s + 2 * h) ^ x7;
        f32x4 uu = *(const f32x4*)(arow + 4 * a0);
        f32x4 vv = *(const f32x4*)(arow + 4 * (a0 ^ 1));
        short8v av;
        av[0] = (short)f2bf(uu.x); av[1] = (short)f2bf(uu.y);
        av[2] = (short)f2bf(uu.z); av[3] = (short)f2bf(uu.w);
        av[4] = (short)f2bf(vv.x); av[5] = (short)f2bf(vv.y);
        av[6] = (short)f2bf(vv.z); av[7] = (short)f2bf(vv.w);
        int qe = (4 * s + h) ^ x7;
#pragma unroll
        for (int f = 0; f < 4; ++f) {
          const unsigned short* brow = &u.g.Bs[buf][(16 * f + r) * KC];
          short8v bv = *(const short8v*)(brow + 8 * qe);
          acc[f] = __builtin_amdgcn_mfma_f32_16x16x32_bf16(av, bv, acc[f], 0, 0, 0);
        }
      }
      __syncthreads();
      buf ^= 1;
    }
#undef STAGE

    // ---- fused gate (verbatim R7, validated): 16-lane groups, 4 tokens each ----
    const int bslot = (m0 >> 11) * E;
    float pxl0 = 0.f, pxl1 = 0.f, pxl2 = 0.f, pxl3 = 0.f;
    float zw = 0.f;
    int c1a[4], c2a[4];
    float g1a[4], g2a[4];
    bool routea[4];

#pragma unroll
    for (int rr = 0; rr < 4; ++rr) {
      float l0 = acc[0][rr], l1 = acc[1][rr], l2 = acc[2][rr], l3 = acc[3][rr];
      float m = fmaxf(fmaxf(l0, l1), fmaxf(l2, l3));
#pragma unroll
      for (int off = 1; off < 16; off <<= 1) m = fmaxf(m, __shfl_xor(m, off));
      float p0 = expf(l0 - m), p1 = expf(l1 - m), p2 = expf(l2 - m), p3 = expf(l3 - m);
      float s = p0 + p1 + p2 + p3;
#pragma unroll
      for (int off = 1; off < 16; off <<= 1) s += __shfl_xor(s, off);

      float m1 = fmaxf(fmaxf(p0, p1), fmaxf(p2, p3));
#pragma unroll
      for (int off = 1; off < 16; off <<= 1) m1 = fmaxf(m1, __shfl_xor(m1, off));
      int lidx = 999;
      if (p0 == m1) lidx = r;
      if (p1 == m1) lidx = min(lidx, 16 + r);
      if (p2 == m1) lidx = min(lidx, 32 + r);
      if (p3 == m1) lidx = min(lidx, 48 + r);
#pragma unroll
      for (int off = 1; off < 16; off <<= 1) lidx = min(lidx, __shfl_xor(lidx, off));
      int c1 = lidx;

      float q0 = (c1 == r) ? -1.f : p0;
      float q1 = (c1 == 16 + r) ? -1.f : p1;
      float q2 = (c1 == 32 + r) ? -1.f : p2;
      float q3 = (c1 == 48 + r) ? -1.f : p3;
      float m2 = fmaxf(fmaxf(q0, q1), fmaxf(q2, q3));
#pragma unroll
      for (int off = 1; off < 16; off <<= 1) m2 = fmaxf(m2, __shfl_xor(m2, off));
      int lidx2 = 999;
      if (q0 == m2) lidx2 = r;
      if (q1 == m2) lidx2 = min(lidx2, 16 + r);
      if (q2 == m2) lidx2 = min(lidx2, 32 + r);
      if (q3 == m2) lidx2 = min(lidx2, 48 + r);
#pragma unroll
      for (int off = 1; off < 16; off <<= 1) lidx2 = min(lidx2, __shfl_xor(lidx2, off));
      int c2 = lidx2;

      float g1 = m1 / s;
      float g2 = m2 / s;
      float denom = g1 + g2 + 1e-9f;
      float g1n = g1 / denom;
      float g2n = g2 / denom;
      int token = m0 + 16 * wv + 4 * h + rr;
      bool route = noise[token] < (g2n / 0.2f);

      c1a[rr] = c1; c2a[rr] = c2; g1a[rr] = g1n; g2a[rr] = g2n; routea[rr] = route;

      pxl0 += p0 / s; pxl1 += p1 / s; pxl2 += p2 / s; pxl3 += p3 / s;
      float lse = m + logf(s);
      zw += lse * lse;
    }

    if (r == 0) {
#pragma unroll
      for (int rr = 0; rr < 4; ++rr) {
        int token = m0 + 16 * wv + 4 * h + rr;
        i1o[token] = c1a[rr];
        i2o[token] = routea[rr] ? c2a[rr] : -1;
        g1o[token] = g1a[rr];
        g2o[token] = g2a[rr];
      }
    }

    pxl0 += __shfl_xor(pxl0, 16); pxl0 += __shfl_xor(pxl0, 32);
    pxl1 += __shfl_xor(pxl1, 16); pxl1 += __shfl_xor(pxl1, 32);
    pxl2 += __shfl_xor(pxl2, 16); pxl2 += __shfl_xor(pxl2, 32);
    pxl3 += __shfl_xor(pxl3, 16); pxl3 += __shfl_xor(pxl3, 32);
    if (l < 16) {
      atomicAdd(&proxyacc[bslot + r], pxl0);
      atomicAdd(&proxyacc[bslot + 16 + r], pxl1);
      atomicAdd(&proxyacc[bslot + 32 + r], pxl2);
      atomicAdd(&proxyacc[bslot + 48 + r], pxl3);
    }
    zw += __shfl_xor(zw, 16); zw += __shfl_xor(zw, 32);
    if (l == 0) zpart[gi * 4 + wv] = zw;

    __syncthreads();
    if (tid == 0) atomicAdd(done, 1);
  }

  // work-stealing fill until all gemm blocks signal done (gemm blocks join too)
  for (;;) {
    if (tid == 0) {
      int c = -1;
      if (atomicAdd(done, 0) < 256) {
        c = atomicAdd(ctr, 1);
        if (c >= NCHUNK) c = -1;
      }
      u.chunk = c;
    }
    __syncthreads();
    int cc = u.chunk;
    __syncthreads();
    if (cc < 0) break;
    const size_t b0 = PH0F4 + (size_t)cc * CHUNK_F4;
#pragma unroll
    for (int i = 0; i < CHUNK_F4 / 256; ++i) o4[b0 + 256 * i + tid] = z4;
  }
  cg::this_grid().sync();

  // ---------------- Phase 2: pos (blocks 8..15) || drain remaining fill ----------------
  if (bid >= 8 && bid < 16) {
    const int b = bid - 8;
    const int wv4 = tid >> 6;
    const int lane = tid & 63;
    const unsigned long long lt = (lane == 63) ? 0x7FFFFFFFFFFFFFFFull
                                               : ((1ull << lane) - 1ull);
#pragma unroll
    for (int ci = 0; ci < 8; ++ci) {
      const int c = wv4 * 8 + ci;
      const int base = c * CHTOK;
      int e1 = i1o[b * NTOK + base + lane];
      int e2 = i2o[b * NTOK + base + lane];
      int p1 = 0, p2 = 0, myc1 = 0, myc2 = 0;
      for (int e = 0; e < E; ++e) {
        unsigned long long m1 = __ballot(e1 == e);
        unsigned long long m2 = __ballot(e2 == e);
        if (e1 == e) p1 = __popcll(m1 & lt);
        if (e2 == e) p2 = __popcll(m2 & lt);
        if (lane == e) { myc1 = __popcll(m1); myc2 = __popcll(m2); }
      }
      u.p.pos1c[base + lane] = (unsigned char)p1;
      u.p.pos2c[base + lane] = (unsigned char)p2;
      u.p.cnt1[c][lane] = myc1;
      u.p.cnt2[c][lane] = myc2;
    }
    __syncthreads();
    if (tid < E) {
      int run1 = 0, run2 = 0;
#pragma unroll 4
      for (int c = 0; c < CHUNKS; ++c) {
        int v1 = u.p.cnt1[c][tid]; u.p.cnt1[c][tid] = run1; run1 += v1;
        int v2 = u.p.cnt2[c][tid]; u.p.cnt2[c][tid] = run2; run2 += v2;
      }
      count1[b * E + tid] = run1;
    }
    __syncthreads();
#pragma unroll
    for (int ci = 0; ci < 8; ++ci) {
      const int c = wv4 * 8 + ci;
      const int base = c * CHTOK;
      const int t = b * NTOK + base + lane;
      int e1 = i1o[t];
      int e2 = i2o[t];
      int pp1 = u.p.cnt1[c][e1] + (int)u.p.pos1c[base + lane];
      int w1 = (pp1 < CAP) ? e1 * CAP + pp1 : -1;
      int w2 = -1;
      if (e2 >= 0) {
        int pp2 = u.p.cnt2[c][e2] + (int)u.p.pos2c[base + lane];
        if (pp2 < CAP) w2 = e2 * CAP + pp2;
      }
      tokinfo[t] = make_int4(w1, w2, __float_as_int(g1o[t]), __float_as_int(g2o[t]));
    }
    __syncthreads();   // protect union before fill loop reuses u.chunk
  }
  // drain all remaining fill chunks (everyone)
  for (;;) {
    if (tid == 0) {
      int c = atomicAdd(ctr, 1);
      u.chunk = (c < NCHUNK) ? c : -1;
    }
    __syncthreads();
    int cc = u.chunk;
    __syncthreads();
    if (cc < 0) break;
    const size_t b0 = PH0F4 + (size_t)cc * CHUNK_F4;
#pragma unroll
    for (int i = 0; i < CHUNK_F4 / 256; ++i) o4[b0 + 256 * i + tid] = z4;
  }
  cg::this_grid().sync();

  // ---------------- Phase 3: sparse scatter + scalar losses ----------------
  const int t = bid * 256 + tid;
  if (t < TOKENS) {
    int4 ti = tokinfo[t];
    float* dispatch = out;
    float* combine = out + OUT_TENSOR;
    if (ti.x >= 0) {
      size_t off = (size_t)t * EC + ti.x;
      combine[off] = __int_as_float(ti.z);
      dispatch[off] = 1.f;
    }
    if (ti.y >= 0) {
      size_t off = (size_t)t * EC + ti.y;
      combine[off] = __int_as_float(ti.w);
      dispatch[off] = 1.f;
    }
  }
  if (bid == 0) {
    float zs = 0.f;
    for (int i = tid; i < 1024; i += 256) zs += zpart[i];
    u.red[tid] = zs;
    __syncthreads();
    for (int s = 128; s > 0; s >>= 1) {
      if (tid < s) u.red[tid] += u.red[tid + s];
      __syncthreads();
    }
    float ztot = u.red[0];
    __syncthreads();
    float bs = 0.f;
    for (int i = tid; i < 512; i += 256) bs += proxyacc[i] * (float)count1[i];
    u.red[tid] = bs;
    __syncthreads();
    for (int s = 128; s > 0; s >>= 1) {
      if (tid < s) u.red[tid] += u.red[tid + s];
      __syncthreads();
    }
    if (tid == 0) {
      out[2 * OUT_TENSOR] = u.red[0] / 524288.f;      // balance_loss
      out[2 * OUT_TENSOR + 1] = ztot / 16384.f;       // router_z_loss
    }
  }
}

extern "C" void kernel_launch(void* const* d_in, const int* in_sizes, int n_in,
                              void* d_out, int out_size, void* d_ws, size_t ws_size,
                              hipStream_t stream) {
  const float* x = (const float*)d_in[0];
  const float* w = (const float*)d_in[1];
  const float* noise = (const float*)d_in[2];
  float* out = (float*)d_out;

  float* ws = (float*)d_ws;
  int* i1 = (int*)ws;                          // 16384
  int* i2r = i1 + TOKENS;                      // 16384
  float* g1 = (float*)(i2r + TOKENS);          // 16384
  float* g2 = g1 + TOKENS;                     // 16384
  float* proxyacc = g2 + TOKENS;               // 512
  int* count1 = (int*)(proxyacc + 512);        // 512
  float* zpart = (float*)(count1 + 512);       // 1024
  unsigned short* wT = (unsigned short*)(zpart + 1024);   // 65536 ushorts
  int4* tokinfo = (int4*)((float*)wT + 32768);             // 16384 int4 (16B-aligned)
  int* ctr = (int*)(tokinfo + TOKENS);
  int* done = ctr + 1;

  void* args[] = {(void*)&x, (void*)&w, (void*)&noise, (void*)&i1, (void*)&i2r,
                  (void*)&g1, (void*)&g2, (void*)&proxyacc, (void*)&count1,
                  (void*)&zpart, (void*)&wT, (void*)&tokinfo, (void*)&ctr,
                  (void*)&done, (void*)&out};
  hipLaunchCooperativeKernel((const void*)k_mega, dim3(512), dim3(256), args, 0, stream);
}

// Round 9
// 143.721 us; speedup vs baseline: 2.4820x; 2.4820x over previous
//
#include <hip/hip_runtime.h>
#include <cstdint>
#include <cstddef>

#define NB 8
#define NTOK 2048
#define TOKENS (NB * NTOK)   // 16384
#define D 1024
#define E 64
#define CAP 40
#define EC (E * CAP)         // 2560
#define OUT_TENSOR ((size_t)TOKENS * EC)  // 41943040
#define CHUNKS 32
#define CHTOK 64
#define KC 64                // gemm k-chunk (floats)

#define TOTAL_F4 20971520ull              // (2*OUT_TENSOR)/4
#define FA 12582912ull                    // K1 fill: 1536 blocks x 8192 f4 (201 MB)
#define FB 3145728ull                     // K2 fill: 1024 blocks x 3072 f4 (50 MB)
// K3 fill: remaining 5242880 f4 = 512 blocks x 10240 (84 MB)

typedef __attribute__((ext_vector_type(8))) short short8v;
typedef __attribute__((ext_vector_type(4))) float f32x4;

__device__ __forceinline__ unsigned short f2bf(float f) {
  unsigned u = __float_as_uint(f);
  unsigned r = (u + 0x7FFFu + ((u >> 16) & 1u)) >> 16;   // RNE
  return (unsigned short)r;
}

__device__ __forceinline__ void gload_lds16(const void* g, void* l) {
  __builtin_amdgcn_global_load_lds(
      (const __attribute__((address_space(1))) void*)g,
      (__attribute__((address_space(3))) void*)l, 16, 0, 0);
}

// ---------------- Kernel 0: wT[e][k] = bf16(w[k][e]); zero proxyacc ----------------
__global__ __launch_bounds__(256) void k_prep(const float* __restrict__ w,
                                              unsigned short* __restrict__ wT,
                                              float* __restrict__ proxyacc) {
  int gid = blockIdx.x * 256 + threadIdx.x;   // 65536 total
  int e = gid >> 10, k = gid & 1023;
  wT[gid] = f2bf(w[k * E + e]);
  if (blockIdx.x == 0 && threadIdx.x < 128)
    reinterpret_cast<float4*>(proxyacc)[threadIdx.x] = make_float4(0.f, 0.f, 0.f, 0.f);
}

// ---------------- Kernel 1: [split-K MFMA gemm blocks || fill blocks] ----------------
// 2048 blocks. (bid&3)==0 -> gemm (512 blocks): gi=bid>>2; m-block gi>>1,
// K-half gi&1 (K=512 each, 8 chunks of KC=64 -> half the R6 dependent chain).
// Staging/compute/fragment math VERBATIM from validated R6 kernel, only the
// chunk count and K offset differ; each half accumulates from 0 and writes its
// own logits buffer (gate sums -> last-ulp rounding change only).
// Other 1536 blocks: contiguous 128 KB zero-fill slices of out[0..FA).
__global__ __launch_bounds__(256, 2) void k_gemm_fill(const float* __restrict__ x,
                                                      const unsigned short* __restrict__ wT,
                                                      float* __restrict__ logits,
                                                      float* __restrict__ out) {
  __shared__ float As[2][64 * KC];            // 2 x 16 KB
  __shared__ unsigned short Bs[2][64 * KC];   // 2 x 8 KB
  const int bid = blockIdx.x;
  const int tid = threadIdx.x;

  if ((bid & 3) != 0) {
    const size_t fi = (size_t)(bid >> 2) * 3 + (bid & 3) - 1;   // 0..1535
    float4* o4 = reinterpret_cast<float4*>(out);
    const float4 z4 = make_float4(0.f, 0.f, 0.f, 0.f);
    const size_t b0 = fi * 8192;
#pragma unroll
    for (int i = 0; i < 32; ++i) o4[b0 + 256 * i + tid] = z4;
    return;
  }

  const int gi = bid >> 2;             // 0..511
  const int m0 = (gi >> 1) * 64;
  const int koff = (gi & 1) << 9;      // 0 or 512
  float* lp = logits + (size_t)(gi & 1) * 1048576;
  const int l = tid & 63;
  const int wv = tid >> 6;
  const int h = l >> 4;
  const int r = l & 15;
  const int x7 = l & 7;

  f32x4 acc[4];
#pragma unroll
  for (int f = 0; f < 4; ++f) acc[f] = (f32x4){0.f, 0.f, 0.f, 0.f};

#define STAGE(BUF, KCOFF)                                                            \
  {                                                                                  \
    _Pragma("unroll") for (int i = 0; i < 4; ++i) {                                  \
      int flat = tid + 256 * i;                                                      \
      int row = flat >> 4, slot = flat & 15;                                         \
      const float* g = x + (size_t)(m0 + row) * D + (KCOFF) + 4 * (slot ^ (row & 7)); \
      gload_lds16(g, (char*)&As[BUF][0] + (flat >> 6) * 1024);                       \
    }                                                                                \
    _Pragma("unroll") for (int i = 0; i < 2; ++i) {                                  \
      int flat = tid + 256 * i;                                                      \
      int e = flat >> 3, slot = flat & 7;                                            \
      const unsigned short* g = wT + (size_t)e * D + (KCOFF) + 8 * (slot ^ (e & 7)); \
      gload_lds16(g, (char*)&Bs[BUF][0] + (flat >> 6) * 1024);                       \
    }                                                                                \
  }

  STAGE(0, koff);
  __syncthreads();
  int buf = 0;
  for (int c = 0; c < 8; ++c) {
    if (c < 7) STAGE(buf ^ 1, koff + (c + 1) * KC);
    const float* arow = &As[buf][(16 * wv + r) * KC];
#pragma unroll
    for (int s = 0; s < 2; ++s) {
      int a0 = (8 * s + 2 * h) ^ x7;
      f32x4 u = *(const f32x4*)(arow + 4 * a0);
      f32x4 v = *(const f32x4*)(arow + 4 * (a0 ^ 1));
      short8v av;
      av[0] = (short)f2bf(u.x); av[1] = (short)f2bf(u.y);
      av[2] = (short)f2bf(u.z); av[3] = (short)f2bf(u.w);
      av[4] = (short)f2bf(v.x); av[5] = (short)f2bf(v.y);
      av[6] = (short)f2bf(v.z); av[7] = (short)f2bf(v.w);
      int qe = (4 * s + h) ^ x7;
#pragma unroll
      for (int f = 0; f < 4; ++f) {
        const unsigned short* brow = &Bs[buf][(16 * f + r) * KC];
        short8v bv = *(const short8v*)(brow + 8 * qe);
        acc[f] = __builtin_amdgcn_mfma_f32_16x16x32_bf16(av, bv, acc[f], 0, 0, 0);
      }
    }
    __syncthreads();
    buf ^= 1;
  }
#undef STAGE

  const int token0 = m0 + 16 * wv + 4 * h;
#pragma unroll
  for (int f = 0; f < 4; ++f)
#pragma unroll
    for (int rr = 0; rr < 4; ++rr)
      lp[(size_t)(token0 + rr) * E + 16 * f + r] = acc[f][rr];
}

// ------------- Kernel 2: [gate blocks || fill blocks] -------------
// Gate VERBATIM validated, except l = lA + lB (split-K sum).
__global__ __launch_bounds__(256) void k_gate_fill(const float* __restrict__ logits,
                                                   const float* __restrict__ noise,
                                                   int* __restrict__ i1o, int* __restrict__ i2o,
                                                   float* __restrict__ g1o, float* __restrict__ g2o,
                                                   float* __restrict__ proxyacc,
                                                   float* __restrict__ zpart,
                                                   float* __restrict__ out) {
  if (blockIdx.x >= 4096) {
    const size_t fi = (size_t)blockIdx.x - 4096;   // 0..1023
    float4* o4 = reinterpret_cast<float4*>(out);
    const float4 z4 = make_float4(0.f, 0.f, 0.f, 0.f);
    const size_t b0 = FA + fi * 3072;
#pragma unroll
    for (int i = 0; i < 12; ++i) o4[b0 + 256 * i + threadIdx.x] = z4;
    return;
  }
  const int wave = threadIdx.x >> 6;
  const int lane = threadIdx.x & 63;
  const int token = (blockIdx.x << 2) + wave;

  float l = logits[(size_t)token * E + lane] + logits[1048576 + (size_t)token * E + lane];
  float m = l;
#pragma unroll
  for (int off = 32; off > 0; off >>= 1) m = fmaxf(m, __shfl_xor(m, off));
  float pe = expf(l - m);
  float s = pe;
#pragma unroll
  for (int off = 32; off > 0; off >>= 1) s += __shfl_xor(s, off);

  float m1 = pe;
#pragma unroll
  for (int off = 32; off > 0; off >>= 1) m1 = fmaxf(m1, __shfl_xor(m1, off));
  int c1 = (pe == m1) ? lane : E;
#pragma unroll
  for (int off = 32; off > 0; off >>= 1) c1 = min(c1, __shfl_xor(c1, off));

  float pe2 = (lane == c1) ? -1.f : pe;
  float m2 = pe2;
#pragma unroll
  for (int off = 32; off > 0; off >>= 1) m2 = fmaxf(m2, __shfl_xor(m2, off));
  int c2 = (pe2 == m2) ? lane : E;
#pragma unroll
  for (int off = 32; off > 0; off >>= 1) c2 = min(c2, __shfl_xor(c2, off));

  float g1 = m1 / s;
  float g2 = m2 / s;
  float denom = g1 + g2 + 1e-9f;
  float g1n = g1 / denom;
  float g2n = g2 / denom;
  bool route = noise[token] < (g2n / 0.2f);

  if (lane == 0) {
    i1o[token] = c1;
    i2o[token] = route ? c2 : -1;
    g1o[token] = g1n;
    g2o[token] = g2n;
  }

  float lse = m + logf(s);
  float zsq = lse * lse;

  __shared__ float sm[4][64];
  __shared__ float zz[4];
  sm[wave][lane] = pe / s;
  if (lane == 0) zz[wave] = zsq;
  __syncthreads();
  if (wave == 0) {
    float sum4 = sm[0][lane] + sm[1][lane] + sm[2][lane] + sm[3][lane];
    atomicAdd(&proxyacc[(token >> 11) * E + lane], sum4);
    if (lane == 0) zpart[blockIdx.x] = zz[0] + zz[1] + zz[2] + zz[3];
  }
}

// ------------- Kernel 3: [pos blocks || fill blocks] -------------
__global__ __launch_bounds__(1024) void k_pos_fill(const int* __restrict__ i1,
                                                   const int* __restrict__ i2r,
                                                   const float* __restrict__ g1,
                                                   const float* __restrict__ g2,
                                                   int4* __restrict__ tokinfo,
                                                   int* __restrict__ count1,
                                                   float* __restrict__ out) {
  const int bid = blockIdx.x;
  if (bid >= NB) {
    const size_t fi = (size_t)bid - NB;   // 0..511
    float4* o4 = reinterpret_cast<float4*>(out);
    const float4 z4 = make_float4(0.f, 0.f, 0.f, 0.f);
    const size_t b0 = FA + FB + fi * 10240;
#pragma unroll
    for (int i = 0; i < 10; ++i) o4[b0 + 1024 * i + threadIdx.x] = z4;
    return;
  }
  __shared__ unsigned char pos1c[NTOK];
  __shared__ unsigned char pos2c[NTOK];
  __shared__ int cnt1[CHUNKS][E];
  __shared__ int cnt2[CHUNKS][E];

  const int b = bid;
  const int tid = threadIdx.x;
  const int wave = tid >> 6;
  const int lane = tid & 63;
  const unsigned long long lt = (lane == 63) ? 0x7FFFFFFFFFFFFFFFull
                                             : ((1ull << lane) - 1ull);

#pragma unroll
  for (int ci = 0; ci < 2; ++ci) {
    const int c = wave * 2 + ci;
    const int base = c * CHTOK;
    int e1 = i1[b * NTOK + base + lane];
    int e2 = i2r[b * NTOK + base + lane];
    int p1 = 0, p2 = 0, myc1 = 0, myc2 = 0;
    for (int e = 0; e < E; ++e) {
      unsigned long long m1 = __ballot(e1 == e);
      unsigned long long m2 = __ballot(e2 == e);
      if (e1 == e) p1 = __popcll(m1 & lt);
      if (e2 == e) p2 = __popcll(m2 & lt);
      if (lane == e) { myc1 = __popcll(m1); myc2 = __popcll(m2); }
    }
    pos1c[base + lane] = (unsigned char)p1;
    pos2c[base + lane] = (unsigned char)p2;
    cnt1[c][lane] = myc1;
    cnt2[c][lane] = myc2;
  }
  __syncthreads();

  if (tid < E) {
    int run1 = 0, run2 = 0;
#pragma unroll 4
    for (int c = 0; c < CHUNKS; ++c) {
      int v1 = cnt1[c][tid]; cnt1[c][tid] = run1; run1 += v1;
      int v2 = cnt2[c][tid]; cnt2[c][tid] = run2; run2 += v2;
    }
    count1[b * E + tid] = run1;   // pre-capacity top-1 totals (density_1)
  }
  __syncthreads();

#pragma unroll
  for (int ci = 0; ci < 2; ++ci) {
    const int c = wave * 2 + ci;
    const int base = c * CHTOK;
    const int t = b * NTOK + base + lane;
    int e1 = i1[t];
    int e2 = i2r[t];
    int pp1 = cnt1[c][e1] + (int)pos1c[base + lane];
    int w1 = (pp1 < CAP) ? e1 * CAP + pp1 : -1;
    int w2 = -1;
    if (e2 >= 0) {
      int pp2 = cnt2[c][e2] + (int)pos2c[base + lane];
      if (pp2 < CAP) w2 = e2 * CAP + pp2;
    }
    tokinfo[t] = make_int4(w1, w2, __float_as_int(g1[t]), __float_as_int(g2[t]));
  }
}

// ------------- Kernel 4: sparse scatter + scalar losses -------------
__global__ __launch_bounds__(256) void k_scatter_final(const int4* __restrict__ tokinfo,
                                                       const float* __restrict__ zpart,
                                                       const float* __restrict__ proxyacc,
                                                       const int* __restrict__ count1,
                                                       float* __restrict__ out) {
  const int t = blockIdx.x * 256 + threadIdx.x;
  const int tid = threadIdx.x;
  if (t < TOKENS) {
    int4 ti = tokinfo[t];
    float* dispatch = out;
    float* combine = out + OUT_TENSOR;
    if (ti.x >= 0) {
      size_t off = (size_t)t * EC + ti.x;
      combine[off] = __int_as_float(ti.z);
      dispatch[off] = 1.f;
    }
    if (ti.y >= 0) {
      size_t off = (size_t)t * EC + ti.y;
      combine[off] = __int_as_float(ti.w);
      dispatch[off] = 1.f;
    }
  }

  if (blockIdx.x == 0) {
    __shared__ float red[256];
    float zs = 0.f;
    for (int i = tid; i < 4096; i += 256) zs += zpart[i];
    red[tid] = zs;
    __syncthreads();
    for (int s = 128; s > 0; s >>= 1) {
      if (tid < s) red[tid] += red[tid + s];
      __syncthreads();
    }
    float ztot = red[0];
    __syncthreads();
    float bs = 0.f;
    for (int i = tid; i < 512; i += 256) bs += proxyacc[i] * (float)count1[i];
    red[tid] = bs;
    __syncthreads();
    for (int s = 128; s > 0; s >>= 1) {
      if (tid < s) red[tid] += red[tid + s];
      __syncthreads();
    }
    if (tid == 0) {
      out[2 * OUT_TENSOR] = red[0] / 524288.f;      // balance_loss
      out[2 * OUT_TENSOR + 1] = ztot / 16384.f;     // router_z_loss
    }
  }
}

extern "C" void kernel_launch(void* const* d_in, const int* in_sizes, int n_in,
                              void* d_out, int out_size, void* d_ws, size_t ws_size,
                              hipStream_t stream) {
  const float* x = (const float*)d_in[0];
  const float* w = (const float*)d_in[1];
  const float* noise = (const float*)d_in[2];
  float* out = (float*)d_out;

  float* ws = (float*)d_ws;
  float* logits = ws;                            // 2 x 1,048,576 floats (split-K)
  int* i1 = (int*)(ws + 2097152);                // 16384
  int* i2r = i1 + TOKENS;                        // 16384
  float* g1 = (float*)(i2r + TOKENS);            // 16384
  float* g2 = g1 + TOKENS;                       // 16384
  float* proxyacc = g2 + TOKENS;                 // 512
  int* count1 = (int*)(proxyacc + 512);          // 512
  float* zpart = (float*)(count1 + 512);         // 4096
  unsigned short* wT = (unsigned short*)(zpart + 4096);   // 65536 ushorts
  int4* tokinfo = (int4*)((float*)wT + 32768);            // 16384 int4 (16B-aligned)

  k_prep<<<256, 256, 0, stream>>>(w, wT, proxyacc);
  k_gemm_fill<<<2048, 256, 0, stream>>>(x, wT, logits, out);
  k_gate_fill<<<5120, 256, 0, stream>>>(logits, noise, i1, i2r, g1, g2, proxyacc, zpart, out);
  k_pos_fill<<<NB + 512, 1024, 0, stream>>>(i1, i2r, g1, g2, tokinfo, count1, out);
  k_scatter_final<<<64, 256, 0, stream>>>(tokinfo, zpart, proxyacc, count1, out);
}

// Round 11
// 110.523 us; speedup vs baseline: 3.2276x; 1.3004x over previous
//
#include <hip/hip_runtime.h>
#include <cstdint>
#include <cstddef>

#define NB 8
#define NTOK 2048
#define TOKENS (NB * NTOK)   // 16384
#define D 1024
#define E 64
#define CAP 40
#define EC (E * CAP)         // 2560
#define OUT_TENSOR ((size_t)TOKENS * EC)  // 41943040
#define CHUNKS 32            // per batch (k_pos)
#define CHTOK 64             // tokens per chunk (k_pos)
#define KC 64                // gemm k-chunk

#define TOTAL_F4 ((2 * OUT_TENSOR) / 4)   // 20,971,520 float4
#define S2 11534336ull       // fill boundary after K2 (184.5 MB)
#define S3 15728640ull       // fill boundary after K3 (+67 MB); K4 fills rest (84 MB)

typedef __attribute__((ext_vector_type(8))) short short8v;
typedef __attribute__((ext_vector_type(4))) float f32x4;

__device__ __forceinline__ unsigned short f2bf(float f) {
  unsigned u = __float_as_uint(f);
  unsigned r = (u + 0x7FFFu + ((u >> 16) & 1u)) >> 16;   // RNE
  return (unsigned short)r;
}

__device__ __forceinline__ void gload_lds16(const void* g, void* l) {
  __builtin_amdgcn_global_load_lds(
      (const __attribute__((address_space(1))) void*)g,
      (__attribute__((address_space(3))) void*)l, 16, 0, 0);
}

// Non-temporal zero store: evict-first, no L2 allocate -> fill traffic stops
// evicting the gemm's L2-resident wT/x lines.
// NOTE: __builtin_nontemporal_store requires a scalar/ext_vector pointer type
// (HIP_vector_type float4 is rejected) -> use clang ext_vector f32x4.
__device__ __forceinline__ void nt_zero(float4* p) {
  __builtin_nontemporal_store((f32x4){0.f, 0.f, 0.f, 0.f},
                              reinterpret_cast<f32x4*>(p));
}

// ---------------- Kernel 0: wT[e][k] = bf16(w[k][e]); zero proxyacc ----------------
__global__ __launch_bounds__(256) void k_prep(const float* __restrict__ w,
                                              unsigned short* __restrict__ wT,
                                              float* __restrict__ proxyacc) {
  int gid = blockIdx.x * 256 + threadIdx.x;   // 65536 total
  int e = gid >> 10, k = gid & 1023;
  wT[gid] = f2bf(w[k * E + e]);
  if (blockIdx.x == 0) {
    proxyacc[threadIdx.x] = 0.f;
    proxyacc[threadIdx.x + 256] = 0.f;
  }
}

// ---------------- Kernel 1: [bf16-MFMA gemm blocks || nt zero-fill blocks] ----------------
// Blocks 0..255: logits = x @ w — VERBATIM from the validated 132.4 µs round-6
// kernel (KC=64, 16 chunks, double-buffered global_load_lds, swizzled source).
// Blocks 256..1023: nt-fill out[0 .. S2).
__global__ __launch_bounds__(256, 1) void k_gemm_fill(const float* __restrict__ x,
                                                      const unsigned short* __restrict__ wT,
                                                      float* __restrict__ logits,
                                                      float* __restrict__ out) {
  __shared__ float As[2][64 * KC];            // 2 x 16 KB
  __shared__ unsigned short Bs[2][64 * KC];   // 2 x 8 KB
  const int tid = threadIdx.x;

  if (blockIdx.x >= 256) {
    float4* o4 = reinterpret_cast<float4*>(out);
    const size_t start = (size_t)(blockIdx.x - 256) * 256 + tid;
    const size_t stride = 768 * 256;
    for (size_t q = start; q < S2; q += stride) nt_zero(&o4[q]);
    return;
  }

  const int m0 = blockIdx.x * 64;
  const int l = tid & 63;
  const int wv = tid >> 6;
  const int h = l >> 4;        // k-group 0..3
  const int r = l & 15;
  const int x7 = l & 7;        // swizzle mask

  f32x4 acc[4];
#pragma unroll
  for (int f = 0; f < 4; ++f) acc[f] = (f32x4){0.f, 0.f, 0.f, 0.f};

#define STAGE(BUF, KCOFF)                                                           \
  {                                                                                 \
    _Pragma("unroll") for (int i = 0; i < 4; ++i) {                                 \
      int flat = tid + 256 * i;            /* 0..1023: 64 rows x 16 slots */        \
      int row = flat >> 4, slot = flat & 15;                                        \
      const float* g = x + (size_t)(m0 + row) * D + (KCOFF) + 4 * (slot ^ (row & 7)); \
      gload_lds16(g, (char*)&As[BUF][0] + (flat >> 6) * 1024);                      \
    }                                                                               \
    _Pragma("unroll") for (int i = 0; i < 2; ++i) {                                 \
      int flat = tid + 256 * i;            /* 0..511: 64 experts x 8 slots */       \
      int e = flat >> 3, slot = flat & 7;                                           \
      const unsigned short* g = wT + (size_t)e * D + (KCOFF) + 8 * (slot ^ (e & 7)); \
      gload_lds16(g, (char*)&Bs[BUF][0] + (flat >> 6) * 1024);                      \
    }                                                                               \
  }

  STAGE(0, 0);
  __syncthreads();
  int buf = 0;
  for (int c = 0; c < 16; ++c) {
    if (c < 15) STAGE(buf ^ 1, (c + 1) * KC);
    const float* arow = &As[buf][(16 * wv + r) * KC];
#pragma unroll
    for (int s = 0; s < 2; ++s) {
      int a0 = (8 * s + 2 * h) ^ x7;
      f32x4 u = *(const f32x4*)(arow + 4 * a0);
      f32x4 v = *(const f32x4*)(arow + 4 * (a0 ^ 1));
      short8v av;
      av[0] = (short)f2bf(u.x); av[1] = (short)f2bf(u.y);
      av[2] = (short)f2bf(u.z); av[3] = (short)f2bf(u.w);
      av[4] = (short)f2bf(v.x); av[5] = (short)f2bf(v.y);
      av[6] = (short)f2bf(v.z); av[7] = (short)f2bf(v.w);
      int qe = (4 * s + h) ^ x7;
#pragma unroll
      for (int f = 0; f < 4; ++f) {
        const unsigned short* brow = &Bs[buf][(16 * f + r) * KC];
        short8v bv = *(const short8v*)(brow + 8 * qe);
        acc[f] = __builtin_amdgcn_mfma_f32_16x16x32_bf16(av, bv, acc[f], 0, 0, 0);
      }
    }
    __syncthreads();
    buf ^= 1;
  }

  const int token0 = m0 + 16 * wv + 4 * h;
#pragma unroll
  for (int f = 0; f < 4; ++f)
#pragma unroll
    for (int rr = 0; rr < 4; ++rr)
      logits[(size_t)(token0 + rr) * E + 16 * f + r] = acc[f][rr];
#undef STAGE
}

// ------------- Kernel 2: [gate blocks || nt fill blocks] -------------
__global__ __launch_bounds__(256) void k_gate_fill(const float* __restrict__ logits,
                                                   const float* __restrict__ noise,
                                                   int* __restrict__ i1o, int* __restrict__ i2o,
                                                   float* __restrict__ g1o, float* __restrict__ g2o,
                                                   float* __restrict__ proxyacc,
                                                   float* __restrict__ zpart,
                                                   float* __restrict__ out) {
  if (blockIdx.x >= 4096) {
    float4* o4 = reinterpret_cast<float4*>(out);
    const size_t start = S2 + (size_t)(blockIdx.x - 4096) * 256 + threadIdx.x;
    const size_t stride = 1024 * 256;
    for (size_t q = start; q < S3; q += stride) nt_zero(&o4[q]);
    return;
  }
  const int wave = threadIdx.x >> 6;
  const int lane = threadIdx.x & 63;
  const int token = (blockIdx.x << 2) + wave;

  float l = logits[(size_t)token * E + lane];
  float m = l;
#pragma unroll
  for (int off = 32; off > 0; off >>= 1) m = fmaxf(m, __shfl_xor(m, off));
  float pe = expf(l - m);
  float s = pe;
#pragma unroll
  for (int off = 32; off > 0; off >>= 1) s += __shfl_xor(s, off);

  float m1 = pe;
#pragma unroll
  for (int off = 32; off > 0; off >>= 1) m1 = fmaxf(m1, __shfl_xor(m1, off));
  int c1 = (pe == m1) ? lane : E;
#pragma unroll
  for (int off = 32; off > 0; off >>= 1) c1 = min(c1, __shfl_xor(c1, off));

  float pe2 = (lane == c1) ? -1.f : pe;
  float m2 = pe2;
#pragma unroll
  for (int off = 32; off > 0; off >>= 1) m2 = fmaxf(m2, __shfl_xor(m2, off));
  int c2 = (pe2 == m2) ? lane : E;
#pragma unroll
  for (int off = 32; off > 0; off >>= 1) c2 = min(c2, __shfl_xor(c2, off));

  float g1 = m1 / s;
  float g2 = m2 / s;
  float denom = g1 + g2 + 1e-9f;
  float g1n = g1 / denom;
  float g2n = g2 / denom;
  bool route = noise[token] < (g2n / 0.2f);

  if (lane == 0) {
    i1o[token] = c1;
    i2o[token] = route ? c2 : -1;
    g1o[token] = g1n;
    g2o[token] = g2n;
  }

  float lse = m + logf(s);
  float zsq = lse * lse;

  __shared__ float sm[4][64];
  __shared__ float zz[4];
  sm[wave][lane] = pe / s;
  if (lane == 0) zz[wave] = zsq;
  __syncthreads();
  if (wave == 0) {
    float sum4 = sm[0][lane] + sm[1][lane] + sm[2][lane] + sm[3][lane];
    atomicAdd(&proxyacc[(token >> 11) * E + lane], sum4);
    if (lane == 0) zpart[blockIdx.x] = zz[0] + zz[1] + zz[2] + zz[3];
  }
}

// ------------- Kernel 3: [pos blocks || nt fill blocks] -------------
__global__ __launch_bounds__(1024) void k_pos_fill(const int* __restrict__ i1,
                                                   const int* __restrict__ i2r,
                                                   const float* __restrict__ g1,
                                                   const float* __restrict__ g2,
                                                   int4* __restrict__ tokinfo,
                                                   int* __restrict__ count1,
                                                   float* __restrict__ out) {
  if (blockIdx.x >= NB) {
    const size_t fi = (size_t)blockIdx.x - NB;   // 0..511
    float4* o4 = reinterpret_cast<float4*>(out);
    for (size_t q = S3 + fi * 1024 + threadIdx.x; q < TOTAL_F4; q += (size_t)512 * 1024)
      nt_zero(&o4[q]);
    return;
  }
  __shared__ unsigned char pos1c[NTOK];
  __shared__ unsigned char pos2c[NTOK];
  __shared__ int cnt1[CHUNKS][E];
  __shared__ int cnt2[CHUNKS][E];

  const int b = blockIdx.x;
  const int tid = threadIdx.x;
  const int wave = tid >> 6;
  const int lane = tid & 63;
  const unsigned long long lt = (lane == 63) ? 0x7FFFFFFFFFFFFFFFull
                                             : ((1ull << lane) - 1ull);

#pragma unroll
  for (int ci = 0; ci < 2; ++ci) {
    const int c = wave * 2 + ci;
    const int base = c * CHTOK;
    int e1 = i1[b * NTOK + base + lane];
    int e2 = i2r[b * NTOK + base + lane];
    int p1 = 0, p2 = 0, myc1 = 0, myc2 = 0;
    for (int e = 0; e < E; ++e) {
      unsigned long long m1 = __ballot(e1 == e);
      unsigned long long m2 = __ballot(e2 == e);
      if (e1 == e) p1 = __popcll(m1 & lt);
      if (e2 == e) p2 = __popcll(m2 & lt);
      if (lane == e) { myc1 = __popcll(m1); myc2 = __popcll(m2); }
    }
    pos1c[base + lane] = (unsigned char)p1;
    pos2c[base + lane] = (unsigned char)p2;
    cnt1[c][lane] = myc1;
    cnt2[c][lane] = myc2;
  }
  __syncthreads();

  if (tid < E) {
    int run1 = 0, run2 = 0;
#pragma unroll 4
    for (int c = 0; c < CHUNKS; ++c) {
      int v1 = cnt1[c][tid]; cnt1[c][tid] = run1; run1 += v1;
      int v2 = cnt2[c][tid]; cnt2[c][tid] = run2; run2 += v2;
    }
    count1[b * E + tid] = run1;   // pre-capacity top-1 totals (density_1)
  }
  __syncthreads();

#pragma unroll
  for (int ci = 0; ci < 2; ++ci) {
    const int c = wave * 2 + ci;
    const int base = c * CHTOK;
    const int t = b * NTOK + base + lane;
    int e1 = i1[t];
    int e2 = i2r[t];
    int pp1 = cnt1[c][e1] + (int)pos1c[base + lane];
    int w1 = (pp1 < CAP) ? e1 * CAP + pp1 : -1;
    int w2 = -1;
    if (e2 >= 0) {
      int pp2 = cnt2[c][e2] + (int)pos2c[base + lane];
      if (pp2 < CAP) w2 = e2 * CAP + pp2;
    }
    tokinfo[t] = make_int4(w1, w2, __float_as_int(g1[t]), __float_as_int(g2[t]));
  }
}

// ------------- Kernel 4: sparse scatter + scalar losses -------------
__global__ __launch_bounds__(256) void k_scatter_final(const int4* __restrict__ tokinfo,
                                                       const float* __restrict__ zpart,
                                                       const float* __restrict__ proxyacc,
                                                       const int* __restrict__ count1,
                                                       float* __restrict__ out) {
  const int t = blockIdx.x * 256 + threadIdx.x;
  const int tid = threadIdx.x;
  if (t < TOKENS) {
    int4 ti = tokinfo[t];
    float* dispatch = out;
    float* combine = out + OUT_TENSOR;
    if (ti.x >= 0) {
      size_t off = (size_t)t * EC + ti.x;
      combine[off] = __int_as_float(ti.z);
      dispatch[off] = 1.f;
    }
    if (ti.y >= 0) {
      size_t off = (size_t)t * EC + ti.y;
      combine[off] = __int_as_float(ti.w);
      dispatch[off] = 1.f;
    }
  }

  if (blockIdx.x == 0) {
    __shared__ float red[256];
    float zs = 0.f;
    for (int i = tid; i < 4096; i += 256) zs += zpart[i];
    red[tid] = zs;
    __syncthreads();
    for (int s = 128; s > 0; s >>= 1) {
      if (tid < s) red[tid] += red[tid + s];
      __syncthreads();
    }
    float ztot = red[0];
    __syncthreads();
    float bs = 0.f;
    for (int i = tid; i < 512; i += 256) bs += proxyacc[i] * (float)count1[i];
    red[tid] = bs;
    __syncthreads();
    for (int s = 128; s > 0; s >>= 1) {
      if (tid < s) red[tid] += red[tid + s];
      __syncthreads();
    }
    if (tid == 0) {
      out[2 * OUT_TENSOR] = red[0] / 524288.f;      // balance_loss
      out[2 * OUT_TENSOR + 1] = ztot / 16384.f;     // router_z_loss
    }
  }
}

extern "C" void kernel_launch(void* const* d_in, const int* in_sizes, int n_in,
                              void* d_out, int out_size, void* d_ws, size_t ws_size,
                              hipStream_t stream) {
  const float* x = (const float*)d_in[0];
  const float* w = (const float*)d_in[1];
  const float* noise = (const float*)d_in[2];
  float* out = (float*)d_out;

  float* ws = (float*)d_ws;
  float* logits = ws;                          // 1,048,576 floats
  int* i1 = (int*)(ws + 1048576);              // 16384
  int* i2r = i1 + TOKENS;                      // 16384
  float* g1 = (float*)(i2r + TOKENS);          // 16384
  float* g2 = g1 + TOKENS;                     // 16384
  float* proxyacc = g2 + TOKENS;               // 512
  int* count1 = (int*)(proxyacc + 512);        // 512
  float* zpart = (float*)(count1 + 512);       // 4096
  unsigned short* wT = (unsigned short*)(zpart + 4096);   // 65536 ushorts
  int4* tokinfo = (int4*)((float*)wT + 32768);            // 16384 int4 (16B-aligned)

  k_prep<<<256, 256, 0, stream>>>(w, wT, proxyacc);
  k_gemm_fill<<<1024, 256, 0, stream>>>(x, wT, logits, out);
  k_gate_fill<<<5120, 256, 0, stream>>>(logits, noise, i1, i2r, g1, g2, proxyacc, zpart, out);
  k_pos_fill<<<NB + 512, 1024, 0, stream>>>(i1, i2r, g1, g2, tokinfo, count1, out);
  k_scatter_final<<<64, 256, 0, stream>>>(tokinfo, zpart, proxyacc, count1, out);
}

// Round 12
// 100.688 us; speedup vs baseline: 3.5429x; 1.0977x over previous
//
#include <hip/hip_runtime.h>
#include <cstdint>
#include <cstddef>

#define NB 8
#define NTOK 2048
#define TOKENS (NB * NTOK)   // 16384
#define D 1024
#define E 64
#define CAP 40
#define EC (E * CAP)         // 2560
#define OUT_TENSOR ((size_t)TOKENS * EC)  // 41943040
#define CHUNKS 32            // per batch (k_pos)
#define CHTOK 64             // tokens per chunk (k_pos)

#define TOTAL_F4 20971520ull // (2*OUT_TENSOR)/4
#define S2 9830400ull        // K1 fill: [0,S2) = 150 MB, 768 blocks x 50 iters exact
#define S3 15204352ull       // K2 fill: [S2,S3) = 82 MB; K3: [S3,TOTAL) = 88 MB (512x1024x11 exact)

typedef __attribute__((ext_vector_type(8))) short short8v;
typedef __attribute__((ext_vector_type(4))) float f32x4;

__device__ __forceinline__ unsigned short f2bf(float f) {
  unsigned u = __float_as_uint(f);
  unsigned r = (u + 0x7FFFu + ((u >> 16) & 1u)) >> 16;   // RNE
  return (unsigned short)r;
}

// Non-temporal zero store (evict-first, no L2 allocate): fill traffic must not
// evict the gemm's L2-resident wT / x lines. Validated +22 us in R11.
__device__ __forceinline__ void nt_zero(float4* p) {
  __builtin_nontemporal_store((f32x4){0.f, 0.f, 0.f, 0.f},
                              reinterpret_cast<f32x4*>(p));
}

// ---------------- Kernel 0: wT[e][k] = bf16(w[k][e]); zero proxyacc ----------------
__global__ __launch_bounds__(256) void k_prep(const float* __restrict__ w,
                                              unsigned short* __restrict__ wT,
                                              float* __restrict__ proxyacc) {
  int gid = blockIdx.x * 256 + threadIdx.x;   // 65536 total
  int e = gid >> 10, k = gid & 1023;
  wT[gid] = f2bf(w[k * E + e]);
  if (blockIdx.x == 0) {
    proxyacc[threadIdx.x] = 0.f;
    proxyacc[threadIdx.x + 256] = 0.f;
  }
}

// ---------------- Kernel 1: [barrier-free reg-pipelined MFMA gemm || nt fill] ----------------
// Blocks 0..255: logits = x @ w. NO LDS, NO barriers: each wave loads its A
// fragments (own 16 token-rows; read-once, 128B/row contiguous across u+v+h)
// and B fragments (contiguous short8v from L2-resident wT) straight to VGPRs,
// 1-chunk-deep double-buffered prefetch, fully unrolled (static reg indices).
// Values and c->s->f MFMA accumulation order identical to the validated R6
// kernel -> bit-identical logits.
// Blocks 256..1023: nt-fill out[0..S2).
__global__ __launch_bounds__(256, 1) void k_gemm_fill(const float* __restrict__ x,
                                                      const unsigned short* __restrict__ wT,
                                                      float* __restrict__ logits,
                                                      float* __restrict__ out) {
  const int tid = threadIdx.x;

  if (blockIdx.x >= 256) {
    float4* o4 = reinterpret_cast<float4*>(out);
    const size_t start = (size_t)(blockIdx.x - 256) * 256 + tid;
    const size_t stride = 768 * 256;
    for (size_t q = start; q < S2; q += stride) nt_zero(&o4[q]);
    return;
  }

  const int m0 = blockIdx.x * 64;
  const int l = tid & 63;
  const int wv = tid >> 6;
  const int h = l >> 4;        // k-subgroup 0..3
  const int r = l & 15;

  const float* xrow = x + (size_t)(m0 + 16 * wv + r) * D;
  const unsigned short* wr0 = wT + (size_t)(r) * D;
  const unsigned short* wr1 = wT + (size_t)(16 + r) * D;
  const unsigned short* wr2 = wT + (size_t)(32 + r) * D;
  const unsigned short* wr3 = wT + (size_t)(48 + r) * D;

  f32x4 acc[4];
#pragma unroll
  for (int f = 0; f < 4; ++f) acc[f] = (f32x4){0.f, 0.f, 0.f, 0.f};

  f32x4 ua[2][2], va[2][2];
  short8v bb[2][2][4];

#define LOAD(BUF, C)                                                   \
  {                                                                    \
    _Pragma("unroll") for (int s = 0; s < 2; ++s) {                    \
      const int k0 = 64 * (C) + 32 * s + 8 * h;                        \
      ua[BUF][s] = *(const f32x4*)(xrow + k0);                         \
      va[BUF][s] = *(const f32x4*)(xrow + k0 + 4);                     \
      bb[BUF][s][0] = *(const short8v*)(wr0 + k0);                     \
      bb[BUF][s][1] = *(const short8v*)(wr1 + k0);                     \
      bb[BUF][s][2] = *(const short8v*)(wr2 + k0);                     \
      bb[BUF][s][3] = *(const short8v*)(wr3 + k0);                     \
    }                                                                  \
  }

  LOAD(0, 0);
#pragma unroll
  for (int c = 0; c < 16; ++c) {
    const int cur = c & 1;              // compile-time under full unroll
    if (c < 15) LOAD((c + 1) & 1, c + 1);
#pragma unroll
    for (int s = 0; s < 2; ++s) {
      f32x4 u = ua[cur][s];
      f32x4 v = va[cur][s];
      short8v av;
      av[0] = (short)f2bf(u.x); av[1] = (short)f2bf(u.y);
      av[2] = (short)f2bf(u.z); av[3] = (short)f2bf(u.w);
      av[4] = (short)f2bf(v.x); av[5] = (short)f2bf(v.y);
      av[6] = (short)f2bf(v.z); av[7] = (short)f2bf(v.w);
#pragma unroll
      for (int f = 0; f < 4; ++f)
        acc[f] = __builtin_amdgcn_mfma_f32_16x16x32_bf16(av, bb[cur][s][f], acc[f], 0, 0, 0);
    }
  }
#undef LOAD

  const int token0 = m0 + 16 * wv + 4 * h;
#pragma unroll
  for (int f = 0; f < 4; ++f)
#pragma unroll
    for (int rr = 0; rr < 4; ++rr)
      logits[(size_t)(token0 + rr) * E + 16 * f + r] = acc[f][rr];
}

// ------------- Kernel 2: [nt fill blocks FIRST || gate blocks] -------------
// Fill dispatched first so the 82 MB stream starts immediately; gate rounds
// interleave behind it.
__global__ __launch_bounds__(256) void k_gate_fill(const float* __restrict__ logits,
                                                   const float* __restrict__ noise,
                                                   int* __restrict__ i1o, int* __restrict__ i2o,
                                                   float* __restrict__ g1o, float* __restrict__ g2o,
                                                   float* __restrict__ proxyacc,
                                                   float* __restrict__ zpart,
                                                   float* __restrict__ out) {
  if (blockIdx.x < 1024) {
    float4* o4 = reinterpret_cast<float4*>(out);
    const size_t start = S2 + (size_t)blockIdx.x * 256 + threadIdx.x;
    const size_t stride = 1024 * 256;
    for (size_t q = start; q < S3; q += stride) nt_zero(&o4[q]);
    return;
  }
  const int gb = blockIdx.x - 1024;    // 0..4095
  const int wave = threadIdx.x >> 6;
  const int lane = threadIdx.x & 63;
  const int token = (gb << 2) + wave;

  float l = logits[(size_t)token * E + lane];
  float m = l;
#pragma unroll
  for (int off = 32; off > 0; off >>= 1) m = fmaxf(m, __shfl_xor(m, off));
  float pe = expf(l - m);
  float s = pe;
#pragma unroll
  for (int off = 32; off > 0; off >>= 1) s += __shfl_xor(s, off);

  float m1 = pe;
#pragma unroll
  for (int off = 32; off > 0; off >>= 1) m1 = fmaxf(m1, __shfl_xor(m1, off));
  int c1 = (pe == m1) ? lane : E;
#pragma unroll
  for (int off = 32; off > 0; off >>= 1) c1 = min(c1, __shfl_xor(c1, off));

  float pe2 = (lane == c1) ? -1.f : pe;
  float m2 = pe2;
#pragma unroll
  for (int off = 32; off > 0; off >>= 1) m2 = fmaxf(m2, __shfl_xor(m2, off));
  int c2 = (pe2 == m2) ? lane : E;
#pragma unroll
  for (int off = 32; off > 0; off >>= 1) c2 = min(c2, __shfl_xor(c2, off));

  float g1 = m1 / s;
  float g2 = m2 / s;
  float denom = g1 + g2 + 1e-9f;
  float g1n = g1 / denom;
  float g2n = g2 / denom;
  bool route = noise[token] < (g2n / 0.2f);

  if (lane == 0) {
    i1o[token] = c1;
    i2o[token] = route ? c2 : -1;
    g1o[token] = g1n;
    g2o[token] = g2n;
  }

  float lse = m + logf(s);
  float zsq = lse * lse;

  __shared__ float sm[4][64];
  __shared__ float zz[4];
  sm[wave][lane] = pe / s;
  if (lane == 0) zz[wave] = zsq;
  __syncthreads();
  if (wave == 0) {
    float sum4 = sm[0][lane] + sm[1][lane] + sm[2][lane] + sm[3][lane];
    atomicAdd(&proxyacc[(token >> 11) * E + lane], sum4);
    if (lane == 0) zpart[gb] = zz[0] + zz[1] + zz[2] + zz[3];
  }
}

// ------------- Kernel 3: [pos blocks || nt fill blocks] -------------
__global__ __launch_bounds__(1024) void k_pos_fill(const int* __restrict__ i1,
                                                   const int* __restrict__ i2r,
                                                   const float* __restrict__ g1,
                                                   const float* __restrict__ g2,
                                                   int4* __restrict__ tokinfo,
                                                   int* __restrict__ count1,
                                                   float* __restrict__ out) {
  if (blockIdx.x >= NB) {
    const size_t fi = (size_t)blockIdx.x - NB;   // 0..511
    float4* o4 = reinterpret_cast<float4*>(out);
    const size_t b0 = S3 + fi * 1024 + threadIdx.x;
#pragma unroll
    for (int i = 0; i < 11; ++i)
      nt_zero(&o4[b0 + (size_t)i * 512 * 1024]);
    return;
  }
  __shared__ unsigned char pos1c[NTOK];
  __shared__ unsigned char pos2c[NTOK];
  __shared__ int cnt1[CHUNKS][E];
  __shared__ int cnt2[CHUNKS][E];

  const int b = blockIdx.x;
  const int tid = threadIdx.x;
  const int wave = tid >> 6;
  const int lane = tid & 63;
  const unsigned long long lt = (lane == 63) ? 0x7FFFFFFFFFFFFFFFull
                                             : ((1ull << lane) - 1ull);

#pragma unroll
  for (int ci = 0; ci < 2; ++ci) {
    const int c = wave * 2 + ci;
    const int base = c * CHTOK;
    int e1 = i1[b * NTOK + base + lane];
    int e2 = i2r[b * NTOK + base + lane];
    int p1 = 0, p2 = 0, myc1 = 0, myc2 = 0;
    for (int e = 0; e < E; ++e) {
      unsigned long long m1 = __ballot(e1 == e);
      unsigned long long m2 = __ballot(e2 == e);
      if (e1 == e) p1 = __popcll(m1 & lt);
      if (e2 == e) p2 = __popcll(m2 & lt);
      if (lane == e) { myc1 = __popcll(m1); myc2 = __popcll(m2); }
    }
    pos1c[base + lane] = (unsigned char)p1;
    pos2c[base + lane] = (unsigned char)p2;
    cnt1[c][lane] = myc1;
    cnt2[c][lane] = myc2;
  }
  __syncthreads();

  if (tid < E) {
    int run1 = 0, run2 = 0;
#pragma unroll 4
    for (int c = 0; c < CHUNKS; ++c) {
      int v1 = cnt1[c][tid]; cnt1[c][tid] = run1; run1 += v1;
      int v2 = cnt2[c][tid]; cnt2[c][tid] = run2; run2 += v2;
    }
    count1[b * E + tid] = run1;   // pre-capacity top-1 totals (density_1)
  }
  __syncthreads();

#pragma unroll
  for (int ci = 0; ci < 2; ++ci) {
    const int c = wave * 2 + ci;
    const int base = c * CHTOK;
    const int t = b * NTOK + base + lane;
    int e1 = i1[t];
    int e2 = i2r[t];
    int pp1 = cnt1[c][e1] + (int)pos1c[base + lane];
    int w1 = (pp1 < CAP) ? e1 * CAP + pp1 : -1;
    int w2 = -1;
    if (e2 >= 0) {
      int pp2 = cnt2[c][e2] + (int)pos2c[base + lane];
      if (pp2 < CAP) w2 = e2 * CAP + pp2;
    }
    tokinfo[t] = make_int4(w1, w2, __float_as_int(g1[t]), __float_as_int(g2[t]));
  }
}

// ------------- Kernel 4: sparse scatter + scalar losses -------------
__global__ __launch_bounds__(256) void k_scatter_final(const int4* __restrict__ tokinfo,
                                                       const float* __restrict__ zpart,
                                                       const float* __restrict__ proxyacc,
                                                       const int* __restrict__ count1,
                                                       float* __restrict__ out) {
  const int t = blockIdx.x * 256 + threadIdx.x;
  const int tid = threadIdx.x;
  if (t < TOKENS) {
    int4 ti = tokinfo[t];
    float* dispatch = out;
    float* combine = out + OUT_TENSOR;
    if (ti.x >= 0) {
      size_t off = (size_t)t * EC + ti.x;
      combine[off] = __int_as_float(ti.z);
      dispatch[off] = 1.f;
    }
    if (ti.y >= 0) {
      size_t off = (size_t)t * EC + ti.y;
      combine[off] = __int_as_float(ti.w);
      dispatch[off] = 1.f;
    }
  }

  if (blockIdx.x == 0) {
    __shared__ float red[256];
    float zs = 0.f;
    for (int i = tid; i < 4096; i += 256) zs += zpart[i];
    red[tid] = zs;
    __syncthreads();
    for (int s = 128; s > 0; s >>= 1) {
      if (tid < s) red[tid] += red[tid + s];
      __syncthreads();
    }
    float ztot = red[0];
    __syncthreads();
    float bs = 0.f;
    for (int i = tid; i < 512; i += 256) bs += proxyacc[i] * (float)count1[i];
    red[tid] = bs;
    __syncthreads();
    for (int s = 128; s > 0; s >>= 1) {
      if (tid < s) red[tid] += red[tid + s];
      __syncthreads();
    }
    if (tid == 0) {
      out[2 * OUT_TENSOR] = red[0] / 524288.f;      // balance_loss
      out[2 * OUT_TENSOR + 1] = ztot / 16384.f;     // router_z_loss
    }
  }
}

extern "C" void kernel_launch(void* const* d_in, const int* in_sizes, int n_in,
                              void* d_out, int out_size, void* d_ws, size_t ws_size,
                              hipStream_t stream) {
  const float* x = (const float*)d_in[0];
  const float* w = (const float*)d_in[1];
  const float* noise = (const float*)d_in[2];
  float* out = (float*)d_out;

  float* ws = (float*)d_ws;
  float* logits = ws;                          // 1,048,576 floats
  int* i1 = (int*)(ws + 1048576);              // 16384
  int* i2r = i1 + TOKENS;                      // 16384
  float* g1 = (float*)(i2r + TOKENS);          // 16384
  float* g2 = g1 + TOKENS;                     // 16384
  float* proxyacc = g2 + TOKENS;               // 512
  int* count1 = (int*)(proxyacc + 512);        // 512
  float* zpart = (float*)(count1 + 512);       // 4096
  unsigned short* wT = (unsigned short*)(zpart + 4096);   // 65536 ushorts
  int4* tokinfo = (int4*)((float*)wT + 32768);            // 16384 int4 (16B-aligned)

  k_prep<<<256, 256, 0, stream>>>(w, wT, proxyacc);
  k_gemm_fill<<<1024, 256, 0, stream>>>(x, wT, logits, out);
  k_gate_fill<<<5120, 256, 0, stream>>>(logits, noise, i1, i2r, g1, g2, proxyacc, zpart, out);
  k_pos_fill<<<NB + 512, 1024, 0, stream>>>(i1, i2r, g1, g2, tokinfo, count1, out);
  k_scatter_final<<<64, 256, 0, stream>>>(tokinfo, zpart, proxyacc, count1, out);
}

// Round 13
// 87.800 us; speedup vs baseline: 4.0629x; 1.1468x over previous
//
#include <hip/hip_runtime.h>
#include <cstdint>
#include <cstddef>

#define NB 8
#define NTOK 2048
#define TOKENS (NB * NTOK)   // 16384
#define D 1024
#define E 64
#define CAP 40
#define EC (E * CAP)         // 2560
#define OUT_TENSOR ((size_t)TOKENS * EC)  // 41943040
#define CHUNKS 32            // per batch (k_pos)
#define CHTOK 64             // tokens per chunk (k_pos)

#define TOTAL_F4 20971520ull // (2*OUT_TENSOR)/4
#define S2 14745600ull       // K1 fill: [0,S2) = 225 MB = 768 blocks x 256 thr x 75 iters exact
                             // K2 fill: [S2,TOTAL) = 95 MB

typedef __attribute__((ext_vector_type(8))) short short8v;
typedef __attribute__((ext_vector_type(4))) float f32x4;

__device__ __forceinline__ unsigned short f2bf(float f) {
  unsigned u = __float_as_uint(f);
  unsigned r = (u + 0x7FFFu + ((u >> 16) & 1u)) >> 16;   // RNE
  return (unsigned short)r;
}

// Non-temporal zero store (evict-first, no L2 allocate). Validated +22 us (R11).
__device__ __forceinline__ void nt_zero(float4* p) {
  __builtin_nontemporal_store((f32x4){0.f, 0.f, 0.f, 0.f},
                              reinterpret_cast<f32x4*>(p));
}

// ---------------- Kernel 0: wT[e][k] = bf16(w[k][e]); zero proxyacc ----------------
__global__ __launch_bounds__(256) void k_prep(const float* __restrict__ w,
                                              unsigned short* __restrict__ wT,
                                              float* __restrict__ proxyacc) {
  int gid = blockIdx.x * 256 + threadIdx.x;   // 65536 total
  int e = gid >> 10, k = gid & 1023;
  wT[gid] = f2bf(w[k * E + e]);
  if (blockIdx.x == 0) {
    proxyacc[threadIdx.x] = 0.f;
    proxyacc[threadIdx.x + 256] = 0.f;
  }
}

// ------- Kernel 1: [barrier-free gemm + IN-REGISTER gate (fused) || nt fill] -------
// Blocks 0..255: logits = x @ w in registers (validated R12 gemm, verbatim),
// then gate directly on the MFMA accumulators (validated R7 fused gate,
// verbatim: 16-lane-group shfl softmax/top-2/route/z/proxy). Logits NEVER
// touch memory. Blocks 256..1023: nt-fill out[0..S2), 75 iters exact.
__global__ __launch_bounds__(256, 1) void k_gemmgate_fill(const float* __restrict__ x,
                                                          const unsigned short* __restrict__ wT,
                                                          const float* __restrict__ noise,
                                                          int* __restrict__ i1o, int* __restrict__ i2o,
                                                          float* __restrict__ g1o, float* __restrict__ g2o,
                                                          float* __restrict__ proxyacc,
                                                          float* __restrict__ zpart,
                                                          float* __restrict__ out) {
  const int tid = threadIdx.x;

  if (blockIdx.x >= 256) {
    float4* o4 = reinterpret_cast<float4*>(out);
    size_t q = (size_t)(blockIdx.x - 256) * 256 + tid;
#pragma unroll 5
    for (int i = 0; i < 75; ++i, q += 768 * 256) nt_zero(&o4[q]);
    return;
  }

  const int m0 = blockIdx.x * 64;
  const int l = tid & 63;
  const int wv = tid >> 6;
  const int h = l >> 4;        // k-subgroup 0..3
  const int r = l & 15;

  const float* xrow = x + (size_t)(m0 + 16 * wv + r) * D;
  const unsigned short* wr0 = wT + (size_t)(r) * D;
  const unsigned short* wr1 = wT + (size_t)(16 + r) * D;
  const unsigned short* wr2 = wT + (size_t)(32 + r) * D;
  const unsigned short* wr3 = wT + (size_t)(48 + r) * D;

  f32x4 acc[4];
#pragma unroll
  for (int f = 0; f < 4; ++f) acc[f] = (f32x4){0.f, 0.f, 0.f, 0.f};

  f32x4 ua[2][2], va[2][2];
  short8v bb[2][2][4];

#define LOAD(BUF, C)                                                   \
  {                                                                    \
    _Pragma("unroll") for (int s = 0; s < 2; ++s) {                    \
      const int k0 = 64 * (C) + 32 * s + 8 * h;                        \
      ua[BUF][s] = *(const f32x4*)(xrow + k0);                         \
      va[BUF][s] = *(const f32x4*)(xrow + k0 + 4);                     \
      bb[BUF][s][0] = *(const short8v*)(wr0 + k0);                     \
      bb[BUF][s][1] = *(const short8v*)(wr1 + k0);                     \
      bb[BUF][s][2] = *(const short8v*)(wr2 + k0);                     \
      bb[BUF][s][3] = *(const short8v*)(wr3 + k0);                     \
    }                                                                  \
  }

  LOAD(0, 0);
#pragma unroll
  for (int c = 0; c < 16; ++c) {
    const int cur = c & 1;              // compile-time under full unroll
    if (c < 15) LOAD((c + 1) & 1, c + 1);
#pragma unroll
    for (int s = 0; s < 2; ++s) {
      f32x4 u = ua[cur][s];
      f32x4 v = va[cur][s];
      short8v av;
      av[0] = (short)f2bf(u.x); av[1] = (short)f2bf(u.y);
      av[2] = (short)f2bf(u.z); av[3] = (short)f2bf(u.w);
      av[4] = (short)f2bf(v.x); av[5] = (short)f2bf(v.y);
      av[6] = (short)f2bf(v.z); av[7] = (short)f2bf(v.w);
#pragma unroll
      for (int f = 0; f < 4; ++f)
        acc[f] = __builtin_amdgcn_mfma_f32_16x16x32_bf16(av, bb[cur][s][f], acc[f], 0, 0, 0);
    }
  }
#undef LOAD

  // ---- fused gate (verbatim validated R7): lane l=16h+r holds
  // acc[f][rr] = logits[token=m0+16wv+4h+rr][expert=16f+r] ----
  const int bslot = (m0 >> 11) * E;
  float pxl0 = 0.f, pxl1 = 0.f, pxl2 = 0.f, pxl3 = 0.f;
  float zw = 0.f;
  int c1a[4], c2a[4];
  float g1a[4], g2a[4];
  bool routea[4];

#pragma unroll
  for (int rr = 0; rr < 4; ++rr) {
    float l0 = acc[0][rr], l1 = acc[1][rr], l2 = acc[2][rr], l3 = acc[3][rr];
    float m = fmaxf(fmaxf(l0, l1), fmaxf(l2, l3));
#pragma unroll
    for (int off = 1; off < 16; off <<= 1) m = fmaxf(m, __shfl_xor(m, off));
    float p0 = expf(l0 - m), p1 = expf(l1 - m), p2 = expf(l2 - m), p3 = expf(l3 - m);
    float s = p0 + p1 + p2 + p3;
#pragma unroll
    for (int off = 1; off < 16; off <<= 1) s += __shfl_xor(s, off);

    float m1 = fmaxf(fmaxf(p0, p1), fmaxf(p2, p3));
#pragma unroll
    for (int off = 1; off < 16; off <<= 1) m1 = fmaxf(m1, __shfl_xor(m1, off));
    int lidx = 999;
    if (p0 == m1) lidx = r;
    if (p1 == m1) lidx = min(lidx, 16 + r);
    if (p2 == m1) lidx = min(lidx, 32 + r);
    if (p3 == m1) lidx = min(lidx, 48 + r);
#pragma unroll
    for (int off = 1; off < 16; off <<= 1) lidx = min(lidx, __shfl_xor(lidx, off));
    int c1 = lidx;

    float q0 = (c1 == r) ? -1.f : p0;
    float q1 = (c1 == 16 + r) ? -1.f : p1;
    float q2 = (c1 == 32 + r) ? -1.f : p2;
    float q3 = (c1 == 48 + r) ? -1.f : p3;
    float m2 = fmaxf(fmaxf(q0, q1), fmaxf(q2, q3));
#pragma unroll
    for (int off = 1; off < 16; off <<= 1) m2 = fmaxf(m2, __shfl_xor(m2, off));
    int lidx2 = 999;
    if (q0 == m2) lidx2 = r;
    if (q1 == m2) lidx2 = min(lidx2, 16 + r);
    if (q2 == m2) lidx2 = min(lidx2, 32 + r);
    if (q3 == m2) lidx2 = min(lidx2, 48 + r);
#pragma unroll
    for (int off = 1; off < 16; off <<= 1) lidx2 = min(lidx2, __shfl_xor(lidx2, off));
    int c2 = lidx2;

    float g1 = m1 / s;
    float g2 = m2 / s;
    float denom = g1 + g2 + 1e-9f;
    float g1n = g1 / denom;
    float g2n = g2 / denom;
    int token = m0 + 16 * wv + 4 * h + rr;
    bool route = noise[token] < (g2n / 0.2f);

    c1a[rr] = c1; c2a[rr] = c2; g1a[rr] = g1n; g2a[rr] = g2n; routea[rr] = route;

    pxl0 += p0 / s; pxl1 += p1 / s; pxl2 += p2 / s; pxl3 += p3 / s;
    float lse = m + logf(s);
    zw += lse * lse;
  }

  if (r == 0) {
#pragma unroll
    for (int rr = 0; rr < 4; ++rr) {
      int token = m0 + 16 * wv + 4 * h + rr;
      i1o[token] = c1a[rr];
      i2o[token] = routea[rr] ? c2a[rr] : -1;
      g1o[token] = g1a[rr];
      g2o[token] = g2a[rr];
    }
  }

  pxl0 += __shfl_xor(pxl0, 16); pxl0 += __shfl_xor(pxl0, 32);
  pxl1 += __shfl_xor(pxl1, 16); pxl1 += __shfl_xor(pxl1, 32);
  pxl2 += __shfl_xor(pxl2, 16); pxl2 += __shfl_xor(pxl2, 32);
  pxl3 += __shfl_xor(pxl3, 16); pxl3 += __shfl_xor(pxl3, 32);
  if (l < 16) {
    atomicAdd(&proxyacc[bslot + r], pxl0);
    atomicAdd(&proxyacc[bslot + 16 + r], pxl1);
    atomicAdd(&proxyacc[bslot + 32 + r], pxl2);
    atomicAdd(&proxyacc[bslot + 48 + r], pxl3);
  }
  zw += __shfl_xor(zw, 16); zw += __shfl_xor(zw, 32);
  if (l == 0) zpart[blockIdx.x * 4 + wv] = zw;
}

// ------------- Kernel 2: [pos blocks || nt fill blocks] -------------
__global__ __launch_bounds__(1024) void k_pos_fill(const int* __restrict__ i1,
                                                   const int* __restrict__ i2r,
                                                   const float* __restrict__ g1,
                                                   const float* __restrict__ g2,
                                                   int4* __restrict__ tokinfo,
                                                   int* __restrict__ count1,
                                                   float* __restrict__ out) {
  if (blockIdx.x >= NB) {
    const size_t fi = (size_t)blockIdx.x - NB;   // 0..511
    float4* o4 = reinterpret_cast<float4*>(out);
    for (size_t q = S2 + fi * 1024 + threadIdx.x; q < TOTAL_F4; q += (size_t)512 * 1024)
      nt_zero(&o4[q]);
    return;
  }
  __shared__ unsigned char pos1c[NTOK];
  __shared__ unsigned char pos2c[NTOK];
  __shared__ int cnt1[CHUNKS][E];
  __shared__ int cnt2[CHUNKS][E];

  const int b = blockIdx.x;
  const int tid = threadIdx.x;
  const int wave = tid >> 6;
  const int lane = tid & 63;
  const unsigned long long lt = (lane == 63) ? 0x7FFFFFFFFFFFFFFFull
                                             : ((1ull << lane) - 1ull);

#pragma unroll
  for (int ci = 0; ci < 2; ++ci) {
    const int c = wave * 2 + ci;
    const int base = c * CHTOK;
    int e1 = i1[b * NTOK + base + lane];
    int e2 = i2r[b * NTOK + base + lane];
    int p1 = 0, p2 = 0, myc1 = 0, myc2 = 0;
    for (int e = 0; e < E; ++e) {
      unsigned long long m1 = __ballot(e1 == e);
      unsigned long long m2 = __ballot(e2 == e);
      if (e1 == e) p1 = __popcll(m1 & lt);
      if (e2 == e) p2 = __popcll(m2 & lt);
      if (lane == e) { myc1 = __popcll(m1); myc2 = __popcll(m2); }
    }
    pos1c[base + lane] = (unsigned char)p1;
    pos2c[base + lane] = (unsigned char)p2;
    cnt1[c][lane] = myc1;
    cnt2[c][lane] = myc2;
  }
  __syncthreads();

  if (tid < E) {
    int run1 = 0, run2 = 0;
#pragma unroll 4
    for (int c = 0; c < CHUNKS; ++c) {
      int v1 = cnt1[c][tid]; cnt1[c][tid] = run1; run1 += v1;
      int v2 = cnt2[c][tid]; cnt2[c][tid] = run2; run2 += v2;
    }
    count1[b * E + tid] = run1;   // pre-capacity top-1 totals (density_1)
  }
  __syncthreads();

#pragma unroll
  for (int ci = 0; ci < 2; ++ci) {
    const int c = wave * 2 + ci;
    const int base = c * CHTOK;
    const int t = b * NTOK + base + lane;
    int e1 = i1[t];
    int e2 = i2r[t];
    int pp1 = cnt1[c][e1] + (int)pos1c[base + lane];
    int w1 = (pp1 < CAP) ? e1 * CAP + pp1 : -1;
    int w2 = -1;
    if (e2 >= 0) {
      int pp2 = cnt2[c][e2] + (int)pos2c[base + lane];
      if (pp2 < CAP) w2 = e2 * CAP + pp2;
    }
    tokinfo[t] = make_int4(w1, w2, __float_as_int(g1[t]), __float_as_int(g2[t]));
  }
}

// ------------- Kernel 3: sparse scatter + scalar losses -------------
__global__ __launch_bounds__(256) void k_scatter_final(const int4* __restrict__ tokinfo,
                                                       const float* __restrict__ zpart,
                                                       const float* __restrict__ proxyacc,
                                                       const int* __restrict__ count1,
                                                       float* __restrict__ out) {
  const int t = blockIdx.x * 256 + threadIdx.x;
  const int tid = threadIdx.x;
  if (t < TOKENS) {
    int4 ti = tokinfo[t];
    float* dispatch = out;
    float* combine = out + OUT_TENSOR;
    if (ti.x >= 0) {
      size_t off = (size_t)t * EC + ti.x;
      combine[off] = __int_as_float(ti.z);
      dispatch[off] = 1.f;
    }
    if (ti.y >= 0) {
      size_t off = (size_t)t * EC + ti.y;
      combine[off] = __int_as_float(ti.w);
      dispatch[off] = 1.f;
    }
  }

  if (blockIdx.x == 0) {
    __shared__ float red[256];
    float zs = 0.f;
    for (int i = tid; i < 1024; i += 256) zs += zpart[i];
    red[tid] = zs;
    __syncthreads();
    for (int s = 128; s > 0; s >>= 1) {
      if (tid < s) red[tid] += red[tid + s];
      __syncthreads();
    }
    float ztot = red[0];
    __syncthreads();
    float bs = 0.f;
    for (int i = tid; i < 512; i += 256) bs += proxyacc[i] * (float)count1[i];
    red[tid] = bs;
    __syncthreads();
    for (int s = 128; s > 0; s >>= 1) {
      if (tid < s) red[tid] += red[tid + s];
      __syncthreads();
    }
    if (tid == 0) {
      out[2 * OUT_TENSOR] = red[0] / 524288.f;      // balance_loss
      out[2 * OUT_TENSOR + 1] = ztot / 16384.f;     // router_z_loss
    }
  }
}

extern "C" void kernel_launch(void* const* d_in, const int* in_sizes, int n_in,
                              void* d_out, int out_size, void* d_ws, size_t ws_size,
                              hipStream_t stream) {
  const float* x = (const float*)d_in[0];
  const float* w = (const float*)d_in[1];
  const float* noise = (const float*)d_in[2];
  float* out = (float*)d_out;

  float* ws = (float*)d_ws;
  int* i1 = (int*)ws;                          // 16384
  int* i2r = i1 + TOKENS;                      // 16384
  float* g1 = (float*)(i2r + TOKENS);          // 16384
  float* g2 = g1 + TOKENS;                     // 16384
  float* proxyacc = g2 + TOKENS;               // 512
  int* count1 = (int*)(proxyacc + 512);        // 512
  float* zpart = (float*)(count1 + 512);       // 1024
  unsigned short* wT = (unsigned short*)(zpart + 1024);   // 65536 ushorts
  int4* tokinfo = (int4*)((float*)wT + 32768);            // 16384 int4 (16B-aligned)

  k_prep<<<256, 256, 0, stream>>>(w, wT, proxyacc);
  k_gemmgate_fill<<<1024, 256, 0, stream>>>(x, wT, noise, i1, i2r, g1, g2,
                                            proxyacc, zpart, out);
  k_pos_fill<<<NB + 512, 1024, 0, stream>>>(i1, i2r, g1, g2, tokinfo, count1, out);
  k_scatter_final<<<64, 256, 0, stream>>>(tokinfo, zpart, proxyacc, count1, out);
}